// Round 16
// baseline (1211.942 us; speedup 1.0000x reference)
//
#include <hip/hip_runtime.h>
#include <math.h>

#define DEV __device__ __forceinline__

typedef __attribute__((ext_vector_type(8))) __bf16 bfrag;
typedef __attribute__((ext_vector_type(4))) float f4;
typedef __attribute__((ext_vector_type(8))) unsigned short u16x8;
typedef __attribute__((ext_vector_type(4))) unsigned short u16x4;

DEV unsigned short f2bf(float f) {
  // native RNE conversion — compiler fuses pairs into v_cvt_pk_bf16_f32 (m240)
  __bf16 b = (__bf16)f;
  unsigned short u;
  __builtin_memcpy(&u, &b, 2);
  return u;
}

DEV void gload_lds16(const void* g, void* l) {
  __builtin_amdgcn_global_load_lds((const __attribute__((address_space(1))) void*)g,
                                   (__attribute__((address_space(3))) void*)l, 16, 0, 0);
}

// ---------------- GEMM 128x128 (m97 structure + XCD chunk) — K=8192, optional split-K ----
// EPI: 0=bias, 1=bias+GELU, 2=bias+residual(f32), 3=split-K atomicAdd (bias only on kh=0,
//      output must already hold the residual/base value).
// nsplit: 1 = normal; 2 = blocks [grid/2, grid) compute the upper K-half.
template<int EPI, int OUTBF, int BIASROW>
__global__ __launch_bounds__(256, 4)
void gemm_bt(const unsigned short* __restrict__ A,
             const unsigned short* __restrict__ Bt,
             const float* __restrict__ bias,
             const float* __restrict__ res,
             void* __restrict__ outp,
             int M, int N, int K, int gm, int cm, int cn, int nsplit)
{
  __shared__ unsigned short As[2][128 * 32];
  __shared__ unsigned short Bs[2][128 * 32];
  const int tid = threadIdx.x;
  const int lane = tid & 63;
  const int wid = tid >> 6;
  const int wr = wid >> 1, wc = wid & 1;
  const int l15 = lane & 15, lg = lane >> 4;

  const int half = gridDim.x >> 1;
  const int kh = (nsplit == 2 && (int)blockIdx.x >= half) ? 1 : 0;
  const int bxid = blockIdx.x - kh * half;
  const int ksub = K / nsplit;
  const long koff = (long)kh * ksub;

  const int xcd = bxid & 7, bidx = bxid >> 3;
  const int cgm = gm / cm;
  const int tm = (xcd % cgm) * cm + bidx % cm;
  const int tn = (xcd / cgm) * cn + bidx / cm;
  const long tM = (long)tm * 128;
  const long tN = (long)tn * 128;

  const int c0 = tid, c1 = tid + 256;
  const int r0 = c0 >> 2, k0 = (c0 & 3) * 8;
  const int r1 = c1 >> 2, k1 = (c1 & 3) * 8;

  const unsigned short* A0 = A + (tM + r0) * (long)K + koff + k0;
  const unsigned short* A1 = A + (tM + r1) * (long)K + koff + k1;
  const unsigned short* B0 = Bt + (tN + r0) * (long)K + koff + k0;
  const unsigned short* B1 = Bt + (tN + r1) * (long)K + koff + k1;

  auto stage = [&](int kt, int buf) {
    const long ko = (long)kt * 32;
    gload_lds16(A0 + ko, &As[buf][c0 * 8]);
    gload_lds16(A1 + ko, &As[buf][c1 * 8]);
    gload_lds16(B0 + ko, &Bs[buf][c0 * 8]);
    gload_lds16(B1 + ko, &Bs[buf][c1 * 8]);
  };

  stage(0, 0);
  f4 acc[4][4] = {};
  const int nk = ksub >> 5;
  int cur = 0;
  __syncthreads();
  for (int kt = 0; kt < nk; ++kt) {
    if (kt + 1 < nk) stage(kt + 1, cur ^ 1);
    bfrag aF[4], bF[4];
#pragma unroll
    for (int m = 0; m < 4; ++m)
      aF[m] = *(const bfrag*)&As[cur][(wr * 64 + m * 16 + l15) * 32 + lg * 8];
#pragma unroll
    for (int n = 0; n < 4; ++n)
      bF[n] = *(const bfrag*)&Bs[cur][(wc * 64 + n * 16 + l15) * 32 + lg * 8];
#pragma unroll
    for (int m = 0; m < 4; ++m)
#pragma unroll
      for (int n = 0; n < 4; ++n)
        acc[m][n] = __builtin_amdgcn_mfma_f32_16x16x32_bf16(aF[m], bF[n], acc[m][n], 0, 0, 0);
    __syncthreads();
    cur ^= 1;
  }

#pragma unroll
  for (int m = 0; m < 4; ++m) {
#pragma unroll
    for (int n = 0; n < 4; ++n) {
      const long col = tN + wc * 64 + n * 16 + l15;
      const float bcol = BIASROW ? 0.f : bias[col];
#pragma unroll
      for (int e = 0; e < 4; ++e) {
        const long row = tM + wr * 64 + m * 16 + lg * 4 + e;
        float v = acc[m][n][e];
        if constexpr (EPI == 3) {
          if (kh == 0) v += (BIASROW ? bias[row] : bcol);
          atomicAdd(&((float*)outp)[row * N + col], v);
        } else {
          v += (BIASROW ? bias[row] : bcol);
          if constexpr (EPI == 1) v = 0.5f * v * (1.0f + erff(v * 0.70710678118654752f));
          if constexpr (EPI == 2) v += res[row * N + col];
          if constexpr (OUTBF) ((unsigned short*)outp)[row * N + col] = f2bf(v);
          else                 ((float*)outp)[row * N + col] = v;
        }
      }
    }
  }
}

// ============ 256x256 8-phase GEMM (R12 schedule, verified) — best for K=3072 ============
template<int EPI, int OUTBF, int BIASROW>
__global__ __launch_bounds__(512, 2)
void gemm256(const unsigned short* __restrict__ A,
             const unsigned short* __restrict__ Bt,
             const float* __restrict__ bias,
             const float* __restrict__ res,
             void* __restrict__ outp,
             int M, int N, int K, int gm, int cm, int cn)
{
  __shared__ unsigned short As[2][256 * 64];
  __shared__ unsigned short Bs[2][256 * 64];

  const int tid = threadIdx.x;
  const int lane = tid & 63;
  const int wid = tid >> 6;
  const int wm = wid >> 2, wn = wid & 3;
  const int l15 = lane & 15, lg = lane >> 4;

  const int xcd = blockIdx.x & 7, bidx = blockIdx.x >> 3;
  const int cgm = gm / cm;
  const int tm = (xcd % cgm) * cm + bidx % cm;
  const int tn = (xcd / cgm) * cn + bidx / cm;
  const long tM = (long)tm * 256, tN = (long)tn * 256;

  const int srow = tid >> 3;
  const int lslot = (tid & 7) ^ (srow & 7);
  const unsigned short* aSrc = A + (tM + srow) * (long)K + lslot * 8;
  const unsigned short* bSrc = Bt + (tN + srow) * (long)K + lslot * 8;
  const int NT = K >> 6;

  auto stA = [&](int t, int j) {
    gload_lds16(aSrc + (long)t * 64 + (long)j * 64 * K, &As[t & 1][j * 4096 + tid * 8]);
  };
  auto stB = [&](int t, int j) {
    gload_lds16(bSrc + (long)t * 64 + (long)j * 64 * K, &Bs[t & 1][j * 4096 + tid * 8]);
  };

#pragma unroll
  for (int j = 0; j < 4; ++j) stA(0, j);
#pragma unroll
  for (int j = 0; j < 4; ++j) stB(0, j);
  stA(1, 0); stA(1, 2);
#pragma unroll
  for (int j = 0; j < 4; ++j) stB(1, j);
  asm volatile("s_waitcnt vmcnt(6)" ::: "memory");
  __builtin_amdgcn_s_barrier();

  const int aRow = (wm * 128 + l15) * 64;
  const int bRow = (wn * 64 + l15) * 64;
  const int sx = l15 & 7;
  const int sl0 = ((0 + lg) ^ sx) * 8;
  const int sl1 = ((4 + lg) ^ sx) * 8;

  bfrag aL[4][2], aH[4][2], b01[2][2], b23[2][2];
  f4 acc[8][4] = {};

  int cur = 0;
  for (int t = 0; t < NT; ++t, cur ^= 1) {
    const unsigned short* Ac = As[cur];
    const unsigned short* Bc = Bs[cur];
    const bool s1 = (t + 1 < NT);
    const bool s2 = (t + 2 < NT);

#pragma unroll
    for (int m = 0; m < 4; ++m) {
      aL[m][0] = *(const bfrag*)&Ac[aRow + m * 1024 + sl0];
      aL[m][1] = *(const bfrag*)&Ac[aRow + m * 1024 + sl1];
    }
#pragma unroll
    for (int n = 0; n < 2; ++n) {
      b01[n][0] = *(const bfrag*)&Bc[bRow + n * 1024 + sl0];
      b01[n][1] = *(const bfrag*)&Bc[bRow + n * 1024 + sl1];
    }
#pragma unroll
    for (int n = 0; n < 2; ++n) {
      b23[n][0] = *(const bfrag*)&Bc[bRow + (n + 2) * 1024 + sl0];
      b23[n][1] = *(const bfrag*)&Bc[bRow + (n + 2) * 1024 + sl1];
    }
    if (s1) { stA(t + 1, 1); stA(t + 1, 3); }
    __builtin_amdgcn_s_barrier();
    __builtin_amdgcn_s_setprio(1);
#pragma unroll
    for (int m = 0; m < 4; ++m)
#pragma unroll
      for (int n = 0; n < 2; ++n) {
        acc[m][n] = __builtin_amdgcn_mfma_f32_16x16x32_bf16(aL[m][0], b01[n][0], acc[m][n], 0, 0, 0);
        acc[m][n] = __builtin_amdgcn_mfma_f32_16x16x32_bf16(aL[m][1], b01[n][1], acc[m][n], 0, 0, 0);
      }
    __builtin_amdgcn_s_setprio(0);
    __builtin_amdgcn_s_barrier();

#pragma unroll
    for (int m = 0; m < 4; ++m) {
      aH[m][0] = *(const bfrag*)&Ac[aRow + 4096 + m * 1024 + sl0];
      aH[m][1] = *(const bfrag*)&Ac[aRow + 4096 + m * 1024 + sl1];
    }
    if (s2) { stA(t + 2, 0); stA(t + 2, 2); }
    __builtin_amdgcn_s_barrier();
    __builtin_amdgcn_s_setprio(1);
#pragma unroll
    for (int m = 0; m < 4; ++m)
#pragma unroll
      for (int n = 0; n < 2; ++n) {
        acc[m][2 + n] = __builtin_amdgcn_mfma_f32_16x16x32_bf16(aL[m][0], b23[n][0], acc[m][2 + n], 0, 0, 0);
        acc[m][2 + n] = __builtin_amdgcn_mfma_f32_16x16x32_bf16(aL[m][1], b23[n][1], acc[m][2 + n], 0, 0, 0);
      }
    __builtin_amdgcn_s_setprio(0);
    __builtin_amdgcn_s_barrier();

    if (s2) { stB(t + 2, 0); stB(t + 2, 1); }
    __builtin_amdgcn_s_barrier();
    __builtin_amdgcn_s_setprio(1);
#pragma unroll
    for (int m = 0; m < 4; ++m)
#pragma unroll
      for (int n = 0; n < 2; ++n) {
        acc[4 + m][2 + n] = __builtin_amdgcn_mfma_f32_16x16x32_bf16(aH[m][0], b23[n][0], acc[4 + m][2 + n], 0, 0, 0);
        acc[4 + m][2 + n] = __builtin_amdgcn_mfma_f32_16x16x32_bf16(aH[m][1], b23[n][1], acc[4 + m][2 + n], 0, 0, 0);
      }
    __builtin_amdgcn_s_setprio(0);
    __builtin_amdgcn_s_barrier();

    if (s2) { stB(t + 2, 2); stB(t + 2, 3); }
    __builtin_amdgcn_s_setprio(1);
#pragma unroll
    for (int m = 0; m < 4; ++m)
#pragma unroll
      for (int n = 0; n < 2; ++n) {
        acc[4 + m][n] = __builtin_amdgcn_mfma_f32_16x16x32_bf16(aH[m][0], b01[n][0], acc[4 + m][n], 0, 0, 0);
        acc[4 + m][n] = __builtin_amdgcn_mfma_f32_16x16x32_bf16(aH[m][1], b01[n][1], acc[4 + m][n], 0, 0, 0);
      }
    __builtin_amdgcn_s_setprio(0);
    if (s2)      asm volatile("s_waitcnt vmcnt(6)" ::: "memory");
    else if (s1) asm volatile("s_waitcnt vmcnt(0)" ::: "memory");
    __builtin_amdgcn_s_barrier();
  }

#pragma unroll
  for (int m = 0; m < 8; ++m) {
    const long row0 = tM + wm * 128 + m * 16 + lg * 4;
#pragma unroll
    for (int n = 0; n < 4; ++n) {
      const long col = tN + wn * 64 + n * 16 + l15;
      const float bc = BIASROW ? 0.f : bias[col];
#pragma unroll
      for (int e = 0; e < 4; ++e) {
        const long row = row0 + e;
        float v = acc[m][n][e] + (BIASROW ? bias[row] : bc);
        if constexpr (EPI == 1) v = 0.5f * v * (1.0f + erff(v * 0.70710678118654752f));
        if constexpr (EPI == 2) v += res[row * N + col];
        if constexpr (OUTBF) ((unsigned short*)outp)[row * N + col] = f2bf(v);
        else                 ((float*)outp)[row * N + col] = v;
      }
    }
  }
}

// ---------------- LayerNorm (f32 in, bf16 out), one block per row of 3072 ----------------
__global__ __launch_bounds__(256)
void ln_bf16(const float* __restrict__ x, const float* __restrict__ g,
             const float* __restrict__ b, unsigned short* __restrict__ out)
{
  __shared__ float red[4];
  const int tid = threadIdx.x;
  const long row = blockIdx.x;
  const float* xr = x + row * 3072;
  float4 v[3];
  float s = 0.f;
#pragma unroll
  for (int i = 0; i < 3; ++i) {
    v[i] = *(const float4*)&xr[i * 1024 + tid * 4];
    s += v[i].x + v[i].y + v[i].z + v[i].w;
  }
#pragma unroll
  for (int o = 32; o > 0; o >>= 1) s += __shfl_xor(s, o);
  if ((tid & 63) == 0) red[tid >> 6] = s;
  __syncthreads();
  s = red[0] + red[1] + red[2] + red[3];
  const float mean = s * (1.f / 3072.f);
  float vs = 0.f;
#pragma unroll
  for (int i = 0; i < 3; ++i) {
    const float dx = v[i].x - mean, dy = v[i].y - mean;
    const float dz = v[i].z - mean, dw = v[i].w - mean;
    vs += dx * dx + dy * dy + dz * dz + dw * dw;
  }
#pragma unroll
  for (int o = 32; o > 0; o >>= 1) vs += __shfl_xor(vs, o);
  __syncthreads();
  if ((tid & 63) == 0) red[tid >> 6] = vs;
  __syncthreads();
  vs = red[0] + red[1] + red[2] + red[3];
  const float rstd = rsqrtf(vs * (1.f / 3072.f) + 1e-5f);
#pragma unroll
  for (int i = 0; i < 3; ++i) {
    const int idx = i * 1024 + tid * 4;
    const float* vp = (const float*)&v[i];
    u16x4 o4;
#pragma unroll
    for (int c = 0; c < 4; ++c)
      o4[c] = f2bf((vp[c] - mean) * rstd * g[idx + c] + b[idx + c]);
    *(u16x4*)&out[row * 3072 + idx] = o4;
  }
}

// -------- fused weight prep v2: 64x64 tiles, float4 loads + u16x4 stores ----------------
__global__ __launch_bounds__(256)
void prep_weights(const float* __restrict__ Wq, const float* __restrict__ Wk,
                  const float* __restrict__ Wv, const float* __restrict__ Wo,
                  const float* __restrict__ W1, const float* __restrict__ W2,
                  const float* __restrict__ bq, const float* __restrict__ bk,
                  unsigned short* __restrict__ WqkT, unsigned short* __restrict__ WvT,
                  unsigned short* __restrict__ WoT, unsigned short* __restrict__ W1T,
                  unsigned short* __restrict__ W2T, float* __restrict__ bqk)
{
  __shared__ float tile[64][65];
  const int tid = threadIdx.x;
  int bid = blockIdx.x;
  if (bid < 24) {  // bias concat: 6144 floats
    const int i = bid * 256 + tid;
    bqk[i] = (i < 3072) ? bq[i] : bk[i - 3072];
    return;
  }
  bid -= 24;
  const float* in; unsigned short* out; int R, C, nbx;
  if (bid < 2304)       { in = Wq; out = WqkT;               R = 3072; C = 3072; nbx = 48; }
  else if (bid < 4608)  { in = Wk; out = WqkT + 3072 * 3072; R = 3072; C = 3072; nbx = 48; bid -= 2304; }
  else if (bid < 6912)  { in = Wv; out = WvT;                R = 3072; C = 3072; nbx = 48; bid -= 4608; }
  else if (bid < 9216)  { in = Wo; out = WoT;                R = 3072; C = 3072; nbx = 48; bid -= 6912; }
  else if (bid < 15360) { in = W1; out = W1T;                R = 3072; C = 8192; nbx = 128; bid -= 9216; }
  else                  { in = W2; out = W2T;                R = 8192; C = 3072; nbx = 48; bid -= 15360; }
  const int bx = bid % nbx, by = bid / nbx;
  const long r0 = (long)by * 64, c0 = (long)bx * 64;
  const int tr = tid >> 4;        // 0..15
  const int tc = (tid & 15) * 4;  // 0,4,..,60

#pragma unroll
  for (int p = 0; p < 4; ++p) {
    const int row = p * 16 + tr;
    const float4 v = *(const float4*)&in[(r0 + row) * C + c0 + tc];
    tile[row][tc + 0] = v.x; tile[row][tc + 1] = v.y;
    tile[row][tc + 2] = v.z; tile[row][tc + 3] = v.w;
  }
  __syncthreads();

#pragma unroll
  for (int q = 0; q < 4; ++q) {
    const int c = q * 16 + tr;
    u16x4 o4;
#pragma unroll
    for (int j = 0; j < 4; ++j)
      o4[j] = f2bf(tile[tc + j][c]);
    *(u16x4*)&out[(c0 + c) * R + r0 + tc] = o4;
  }
}

// ---------------- Flash attention fwd (R14: Q-in-reg, T14 K/V reg-prefetch, defer-max) ----
__global__ __launch_bounds__(256, 4)
void attn_fwd(const unsigned short* __restrict__ qk,
              const unsigned short* __restrict__ vT,
              unsigned short* __restrict__ ctx)
{
  __shared__ unsigned short Ks[64 * 104];
  __shared__ unsigned short Vt[96 * 72];
  __shared__ unsigned short Ps[4 * 16 * 72];
  const int tid = threadIdx.x;
  const int lane = tid & 63;
  const int w = tid >> 6;
  const int l15 = lane & 15, lg = lane >> 4;
  const int bid = (blockIdx.x & 7) * 256 + (blockIdx.x >> 3);
  const int qb = bid & 31;
  const int h = (bid >> 5) & 31;
  const int b = bid >> 10;
  const long qkbase = ((long)b * 2048) * 6144 + h * 96;
  const long obase  = ((long)b * 2048) * 3072 + h * 96;
  const long vbase  = (long)(h * 96) * 4096 + (long)b * 2048;
  const int qbase = qb * 64;

  bfrag qf[3];
#pragma unroll
  for (int ks = 0; ks < 3; ++ks)
    qf[ks] = *(const bfrag*)&qk[qkbase + (long)(qbase + w * 16 + l15) * 6144 + ks * 32 + lg * 8];

  const int kr0 = tid / 12,         kk0 = (tid % 12) * 8;
  const int kr1 = (tid + 256) / 12, kk1 = ((tid + 256) % 12) * 8;
  const int kr2 = (tid + 512) / 12, kk2 = ((tid + 512) % 12) * 8;
  const unsigned short* kg = qk + qkbase + 3072;
  const int vd0 = tid >> 3,           vk0 = (tid & 7) * 8;
  const int vd1 = (tid + 256) >> 3,   vk1 = ((tid + 256) & 7) * 8;
  const int vd2 = (tid + 512) >> 3,   vk2 = ((tid + 512) & 7) * 8;
  const unsigned short* vg = vT + vbase;

  u16x8 kA = *(const u16x8*)&kg[(long)kr0 * 6144 + kk0];
  u16x8 kB = *(const u16x8*)&kg[(long)kr1 * 6144 + kk1];
  u16x8 kC = *(const u16x8*)&kg[(long)kr2 * 6144 + kk2];
  u16x8 vA = *(const u16x8*)&vg[(long)vd0 * 4096 + vk0];
  u16x8 vB = *(const u16x8*)&vg[(long)vd1 * 4096 + vk1];
  u16x8 vC = *(const u16x8*)&vg[(long)vd2 * 4096 + vk2];

  float m_run = -1e30f, l_run = 0.f;
  f4 O[6] = {};
  const float sc = 0.1020620726f * 1.4426950409f;  // 1/sqrt(96) * log2(e)

  for (int t = 0; t < 32; ++t) {
    *(u16x8*)&Ks[kr0 * 104 + kk0] = kA;
    *(u16x8*)&Ks[kr1 * 104 + kk1] = kB;
    *(u16x8*)&Ks[kr2 * 104 + kk2] = kC;
    *(u16x8*)&Vt[vd0 * 72 + vk0] = vA;
    *(u16x8*)&Vt[vd1 * 72 + vk1] = vB;
    *(u16x8*)&Vt[vd2 * 72 + vk2] = vC;
    __syncthreads();
    if (t + 1 < 32) {
      const long ko = (long)(t + 1) * 64 * 6144;
      const long vo = (long)(t + 1) * 64;
      kA = *(const u16x8*)&kg[ko + (long)kr0 * 6144 + kk0];
      kB = *(const u16x8*)&kg[ko + (long)kr1 * 6144 + kk1];
      kC = *(const u16x8*)&kg[ko + (long)kr2 * 6144 + kk2];
      vA = *(const u16x8*)&vg[vo + (long)vd0 * 4096 + vk0];
      vB = *(const u16x8*)&vg[vo + (long)vd1 * 4096 + vk1];
      vC = *(const u16x8*)&vg[vo + (long)vd2 * 4096 + vk2];
    }

    f4 sf[4];
#pragma unroll
    for (int mb = 0; mb < 4; ++mb) {
      f4 z = {0.f, 0.f, 0.f, 0.f};
      sf[mb] = z;
#pragma unroll
      for (int ks = 0; ks < 3; ++ks) {
        bfrag kf = *(const bfrag*)&Ks[(mb * 16 + l15) * 104 + ks * 32 + lg * 8];
        sf[mb] = __builtin_amdgcn_mfma_f32_16x16x32_bf16(kf, qf[ks], sf[mb], 0, 0, 0);
      }
    }
    float p[16];
    float tmax = -1e30f;
#pragma unroll
    for (int mb = 0; mb < 4; ++mb)
#pragma unroll
      for (int e = 0; e < 4; ++e) {
        const float sv = sf[mb][e] * sc;
        p[mb * 4 + e] = sv;
        tmax = fmaxf(tmax, sv);
      }
    tmax = fmaxf(tmax, __shfl_xor(tmax, 16));
    tmax = fmaxf(tmax, __shfl_xor(tmax, 32));
    const bool noskip = !__all(tmax - m_run <= 8.0f);
    float mnew = m_run, alpha = 1.0f;
    if (noskip) {
      mnew = fmaxf(m_run, tmax);
      alpha = exp2f(m_run - mnew);
    }
    float psum = 0.f;
#pragma unroll
    for (int i = 0; i < 16; ++i) {
      p[i] = exp2f(p[i] - mnew);
      psum += p[i];
    }
    psum += __shfl_xor(psum, 16);
    psum += __shfl_xor(psum, 32);
    l_run = l_run * alpha + psum;
    m_run = mnew;
#pragma unroll
    for (int mb = 0; mb < 4; ++mb) {
      u16x4 pw;
#pragma unroll
      for (int e = 0; e < 4; ++e) pw[e] = f2bf(p[mb * 4 + e]);
      *(u16x4*)&Ps[w * 1152 + l15 * 72 + mb * 16 + lg * 4] = pw;
    }
    if (noskip) {
      float aE[4];
#pragma unroll
      for (int e = 0; e < 4; ++e) aE[e] = __shfl(alpha, lg * 4 + e);
#pragma unroll
      for (int nb = 0; nb < 6; ++nb)
#pragma unroll
        for (int e = 0; e < 4; ++e) O[nb][e] *= aE[e];
    }
    bfrag pf[2];
#pragma unroll
    for (int ks = 0; ks < 2; ++ks)
      pf[ks] = *(const bfrag*)&Ps[w * 1152 + l15 * 72 + ks * 32 + lg * 8];
#pragma unroll
    for (int nb = 0; nb < 6; ++nb)
#pragma unroll
      for (int ks = 0; ks < 2; ++ks) {
        bfrag vf = *(const bfrag*)&Vt[(nb * 16 + l15) * 72 + ks * 32 + lg * 8];
        O[nb] = __builtin_amdgcn_mfma_f32_16x16x32_bf16(pf[ks], vf, O[nb], 0, 0, 0);
      }
    __syncthreads();
  }
  float lE[4];
#pragma unroll
  for (int e = 0; e < 4; ++e) lE[e] = 1.f / __shfl(l_run, lg * 4 + e);
#pragma unroll
  for (int nb = 0; nb < 6; ++nb)
#pragma unroll
    for (int e = 0; e < 4; ++e) {
      const long row = qbase + w * 16 + lg * 4 + e;
      ctx[obase + row * 3072 + nb * 16 + l15] = f2bf(O[nb][e] * lE[e]);
    }
}

// ---------------- driver ----------------
extern "C" void kernel_launch(void* const* d_in, const int* in_sizes, int n_in,
                              void* d_out, int out_size, void* d_ws, size_t ws_size,
                              hipStream_t stream)
{
  (void)in_sizes; (void)n_in; (void)out_size; (void)ws_size;
  const float* x    = (const float*)d_in[0];
  const float* ln1g = (const float*)d_in[1];
  const float* ln1b = (const float*)d_in[2];
  const float* Wq   = (const float*)d_in[3];
  const float* bq   = (const float*)d_in[4];
  const float* Wk   = (const float*)d_in[5];
  const float* bk   = (const float*)d_in[6];
  const float* Wv   = (const float*)d_in[7];
  const float* bv   = (const float*)d_in[8];
  const float* Wo   = (const float*)d_in[9];
  const float* bo   = (const float*)d_in[10];
  const float* ln2g = (const float*)d_in[11];
  const float* ln2b = (const float*)d_in[12];
  const float* W1   = (const float*)d_in[13];
  const float* b1   = (const float*)d_in[14];
  const float* W2   = (const float*)d_in[15];
  const float* b2   = (const float*)d_in[16];

  char* ws = (char*)d_ws;
  unsigned short* WqkT = (unsigned short*)(ws + 0);          // [6144][3072]
  unsigned short* WvT  = (unsigned short*)(ws + 37748736);   // [3072][3072]
  unsigned short* WoT  = (unsigned short*)(ws + 56623104);   // [3072][3072]
  unsigned short* W1T  = (unsigned short*)(ws + 75497472);   // [8192][3072]
  unsigned short* W2T  = (unsigned short*)(ws + 125829120);  // [3072][8192]
  float*          bqk  = (float*)(ws + 176160768);           // [6144]
  unsigned short* hbf  = (unsigned short*)(ws + 176185344);  // LN1 out; later ctx
  unsigned short* ctxb = hbf;
  unsigned short* qkb  = (unsigned short*)(ws + 201351168);  // [4096][6144]; later h2
  unsigned short* h2   = qkb;
  unsigned short* act  = (unsigned short*)(ws + 251682816);  // [4096][8192]
  unsigned short* vTb  = (unsigned short*)(ws + 318791680);  // [3072][4096]
  float*          h1   = (float*)d_out;                      // f32 residual lives in d_out

  const dim3 blk(256);
  const dim3 blk512(512);

  // weight prep: 24 bias blocks + 21504 transpose tiles (64x64)
  prep_weights<<<24 + 21504, blk, 0, stream>>>(Wq, Wk, Wv, Wo, W1, W2, bq, bk,
                                               WqkT, WvT, WoT, W1T, W2T, bqk);

  ln_bf16<<<4096, blk, 0, stream>>>(x, ln1g, ln1b, hbf);

  // fused Q+K projection (K=3072): gemm256, 16x24 tiles = 384 blocks, chunk 8x6
  gemm256<0, 1, 0><<<384, blk512, 0, stream>>>(hbf, WqkT, bqk, nullptr, qkb, 4096, 6144, 3072, 16, 8, 6);
  // V projection, swapped operands -> vT [3072][4096] (K=3072): 12x16 = 192, chunk 6x4
  gemm256<0, 1, 1><<<192, blk512, 0, stream>>>(WvT, hbf, bv, nullptr, vTb, 3072, 4096, 3072, 12, 6, 4);

  attn_fwd<<<2048, blk, 0, stream>>>(qkb, vTb, ctxb);

  // O projection + residual(x) -> h1 (f32, in d_out) (K=3072): 16x12 = 192, chunk 4x6
  gemm256<2, 0, 0><<<192, blk512, 0, stream>>>(ctxb, WoT, bo, x, h1, 4096, 3072, 3072, 16, 4, 6);

  ln_bf16<<<4096, blk, 0, stream>>>(h1, ln2g, ln2b, h2);

  // MLP up + GELU (K=3072): gemm256, 512 blocks = exactly 2 full machine rounds
  gemm256<1, 1, 0><<<512, blk512, 0, stream>>>(h2, W1T, b1, nullptr, act, 4096, 8192, 3072, 16, 8, 8);
  // MLP down (K=8192): split-K=2 atomicAdd into d_out (which already holds h1).
  // 1536 blocks = 6/CU static, ~5 resident -> hides the m97 barrier drain.
  gemm_bt<3, 0, 0><<<1536, blk, 0, stream>>>(act, W2T, b2, nullptr, (float*)d_out,
                                             4096, 3072, 8192, 32, 16, 6, 2);
}

// Round 17
// 1169.120 us; speedup vs baseline: 1.0366x; 1.0366x over previous
//
#include <hip/hip_runtime.h>
#include <math.h>

#define DEV __device__ __forceinline__

typedef __attribute__((ext_vector_type(8))) __bf16 bfrag;
typedef __attribute__((ext_vector_type(4))) float f4;
typedef __attribute__((ext_vector_type(8))) unsigned short u16x8;
typedef __attribute__((ext_vector_type(4))) unsigned short u16x4;

DEV unsigned short f2bf(float f) {
  // native RNE conversion — compiler fuses pairs into v_cvt_pk_bf16_f32 (m240)
  __bf16 b = (__bf16)f;
  unsigned short u;
  __builtin_memcpy(&u, &b, 2);
  return u;
}

DEV void gload_lds16(const void* g, void* l) {
  __builtin_amdgcn_global_load_lds((const __attribute__((address_space(1))) void*)g,
                                   (__attribute__((address_space(3))) void*)l, 16, 0, 0);
}

// ---------------- GEMM 128x128 (m97 structure + XCD chunk) — best for K=8192 ----------------
// EPI: 0=bias, 1=bias+GELU, 2=bias+residual(f32). (R16's split-K path removed: atomics
// doubled WRITE_SIZE and panel re-fetch — 260->306 us regression.)
template<int EPI, int OUTBF, int BIASROW>
__global__ __launch_bounds__(256, 2)
void gemm_bt(const unsigned short* __restrict__ A,
             const unsigned short* __restrict__ Bt,
             const float* __restrict__ bias,
             const float* __restrict__ res,
             void* __restrict__ outp,
             int M, int N, int K, int gm, int cm, int cn)
{
  __shared__ unsigned short As[2][128 * 32];
  __shared__ unsigned short Bs[2][128 * 32];
  const int tid = threadIdx.x;
  const int lane = tid & 63;
  const int wid = tid >> 6;
  const int wr = wid >> 1, wc = wid & 1;
  const int l15 = lane & 15, lg = lane >> 4;

  const int xcd = blockIdx.x & 7, bidx = blockIdx.x >> 3;
  const int cgm = gm / cm;
  const int tm = (xcd % cgm) * cm + bidx % cm;
  const int tn = (xcd / cgm) * cn + bidx / cm;
  const long tM = (long)tm * 128;
  const long tN = (long)tn * 128;

  const int c0 = tid, c1 = tid + 256;
  const int r0 = c0 >> 2, k0 = (c0 & 3) * 8;
  const int r1 = c1 >> 2, k1 = (c1 & 3) * 8;

  const unsigned short* A0 = A + (tM + r0) * (long)K + k0;
  const unsigned short* A1 = A + (tM + r1) * (long)K + k1;
  const unsigned short* B0 = Bt + (tN + r0) * (long)K + k0;
  const unsigned short* B1 = Bt + (tN + r1) * (long)K + k1;

  auto stage = [&](int kt, int buf) {
    const long ko = (long)kt * 32;
    gload_lds16(A0 + ko, &As[buf][c0 * 8]);
    gload_lds16(A1 + ko, &As[buf][c1 * 8]);
    gload_lds16(B0 + ko, &Bs[buf][c0 * 8]);
    gload_lds16(B1 + ko, &Bs[buf][c1 * 8]);
  };

  stage(0, 0);
  f4 acc[4][4] = {};
  const int nk = K >> 5;
  int cur = 0;
  __syncthreads();
  for (int kt = 0; kt < nk; ++kt) {
    if (kt + 1 < nk) stage(kt + 1, cur ^ 1);
    bfrag aF[4], bF[4];
#pragma unroll
    for (int m = 0; m < 4; ++m)
      aF[m] = *(const bfrag*)&As[cur][(wr * 64 + m * 16 + l15) * 32 + lg * 8];
#pragma unroll
    for (int n = 0; n < 4; ++n)
      bF[n] = *(const bfrag*)&Bs[cur][(wc * 64 + n * 16 + l15) * 32 + lg * 8];
#pragma unroll
    for (int m = 0; m < 4; ++m)
#pragma unroll
      for (int n = 0; n < 4; ++n)
        acc[m][n] = __builtin_amdgcn_mfma_f32_16x16x32_bf16(aF[m], bF[n], acc[m][n], 0, 0, 0);
    __syncthreads();
    cur ^= 1;
  }

#pragma unroll
  for (int m = 0; m < 4; ++m) {
#pragma unroll
    for (int n = 0; n < 4; ++n) {
      const long col = tN + wc * 64 + n * 16 + l15;
      const float bcol = BIASROW ? 0.f : bias[col];
#pragma unroll
      for (int e = 0; e < 4; ++e) {
        const long row = tM + wr * 64 + m * 16 + lg * 4 + e;
        float v = acc[m][n][e] + (BIASROW ? bias[row] : bcol);
        if constexpr (EPI == 1) v = 0.5f * v * (1.0f + erff(v * 0.70710678118654752f));
        if constexpr (EPI == 2) v += res[row * N + col];
        if constexpr (OUTBF) ((unsigned short*)outp)[row * N + col] = f2bf(v);
        else                 ((float*)outp)[row * N + col] = v;
      }
    }
  }
}

// ============ 256x256 8-phase GEMM (R12 schedule, verified) — best for K=3072 ============
template<int EPI, int OUTBF, int BIASROW>
__global__ __launch_bounds__(512, 2)
void gemm256(const unsigned short* __restrict__ A,
             const unsigned short* __restrict__ Bt,
             const float* __restrict__ bias,
             const float* __restrict__ res,
             void* __restrict__ outp,
             int M, int N, int K, int gm, int cm, int cn)
{
  __shared__ unsigned short As[2][256 * 64];
  __shared__ unsigned short Bs[2][256 * 64];

  const int tid = threadIdx.x;
  const int lane = tid & 63;
  const int wid = tid >> 6;
  const int wm = wid >> 2, wn = wid & 3;
  const int l15 = lane & 15, lg = lane >> 4;

  const int xcd = blockIdx.x & 7, bidx = blockIdx.x >> 3;
  const int cgm = gm / cm;
  const int tm = (xcd % cgm) * cm + bidx % cm;
  const int tn = (xcd / cgm) * cn + bidx / cm;
  const long tM = (long)tm * 256, tN = (long)tn * 256;

  const int srow = tid >> 3;
  const int lslot = (tid & 7) ^ (srow & 7);
  const unsigned short* aSrc = A + (tM + srow) * (long)K + lslot * 8;
  const unsigned short* bSrc = Bt + (tN + srow) * (long)K + lslot * 8;
  const int NT = K >> 6;

  auto stA = [&](int t, int j) {
    gload_lds16(aSrc + (long)t * 64 + (long)j * 64 * K, &As[t & 1][j * 4096 + tid * 8]);
  };
  auto stB = [&](int t, int j) {
    gload_lds16(bSrc + (long)t * 64 + (long)j * 64 * K, &Bs[t & 1][j * 4096 + tid * 8]);
  };

#pragma unroll
  for (int j = 0; j < 4; ++j) stA(0, j);
#pragma unroll
  for (int j = 0; j < 4; ++j) stB(0, j);
  stA(1, 0); stA(1, 2);
#pragma unroll
  for (int j = 0; j < 4; ++j) stB(1, j);
  asm volatile("s_waitcnt vmcnt(6)" ::: "memory");
  __builtin_amdgcn_s_barrier();

  const int aRow = (wm * 128 + l15) * 64;
  const int bRow = (wn * 64 + l15) * 64;
  const int sx = l15 & 7;
  const int sl0 = ((0 + lg) ^ sx) * 8;
  const int sl1 = ((4 + lg) ^ sx) * 8;

  bfrag aL[4][2], aH[4][2], b01[2][2], b23[2][2];
  f4 acc[8][4] = {};

  int cur = 0;
  for (int t = 0; t < NT; ++t, cur ^= 1) {
    const unsigned short* Ac = As[cur];
    const unsigned short* Bc = Bs[cur];
    const bool s1 = (t + 1 < NT);
    const bool s2 = (t + 2 < NT);

#pragma unroll
    for (int m = 0; m < 4; ++m) {
      aL[m][0] = *(const bfrag*)&Ac[aRow + m * 1024 + sl0];
      aL[m][1] = *(const bfrag*)&Ac[aRow + m * 1024 + sl1];
    }
#pragma unroll
    for (int n = 0; n < 2; ++n) {
      b01[n][0] = *(const bfrag*)&Bc[bRow + n * 1024 + sl0];
      b01[n][1] = *(const bfrag*)&Bc[bRow + n * 1024 + sl1];
    }
#pragma unroll
    for (int n = 0; n < 2; ++n) {
      b23[n][0] = *(const bfrag*)&Bc[bRow + (n + 2) * 1024 + sl0];
      b23[n][1] = *(const bfrag*)&Bc[bRow + (n + 2) * 1024 + sl1];
    }
    if (s1) { stA(t + 1, 1); stA(t + 1, 3); }
    __builtin_amdgcn_s_barrier();
    __builtin_amdgcn_s_setprio(1);
#pragma unroll
    for (int m = 0; m < 4; ++m)
#pragma unroll
      for (int n = 0; n < 2; ++n) {
        acc[m][n] = __builtin_amdgcn_mfma_f32_16x16x32_bf16(aL[m][0], b01[n][0], acc[m][n], 0, 0, 0);
        acc[m][n] = __builtin_amdgcn_mfma_f32_16x16x32_bf16(aL[m][1], b01[n][1], acc[m][n], 0, 0, 0);
      }
    __builtin_amdgcn_s_setprio(0);
    __builtin_amdgcn_s_barrier();

#pragma unroll
    for (int m = 0; m < 4; ++m) {
      aH[m][0] = *(const bfrag*)&Ac[aRow + 4096 + m * 1024 + sl0];
      aH[m][1] = *(const bfrag*)&Ac[aRow + 4096 + m * 1024 + sl1];
    }
    if (s2) { stA(t + 2, 0); stA(t + 2, 2); }
    __builtin_amdgcn_s_barrier();
    __builtin_amdgcn_s_setprio(1);
#pragma unroll
    for (int m = 0; m < 4; ++m)
#pragma unroll
      for (int n = 0; n < 2; ++n) {
        acc[m][2 + n] = __builtin_amdgcn_mfma_f32_16x16x32_bf16(aL[m][0], b23[n][0], acc[m][2 + n], 0, 0, 0);
        acc[m][2 + n] = __builtin_amdgcn_mfma_f32_16x16x32_bf16(aL[m][1], b23[n][1], acc[m][2 + n], 0, 0, 0);
      }
    __builtin_amdgcn_s_setprio(0);
    __builtin_amdgcn_s_barrier();

    if (s2) { stB(t + 2, 0); stB(t + 2, 1); }
    __builtin_amdgcn_s_barrier();
    __builtin_amdgcn_s_setprio(1);
#pragma unroll
    for (int m = 0; m < 4; ++m)
#pragma unroll
      for (int n = 0; n < 2; ++n) {
        acc[4 + m][2 + n] = __builtin_amdgcn_mfma_f32_16x16x32_bf16(aH[m][0], b23[n][0], acc[4 + m][2 + n], 0, 0, 0);
        acc[4 + m][2 + n] = __builtin_amdgcn_mfma_f32_16x16x32_bf16(aH[m][1], b23[n][1], acc[4 + m][2 + n], 0, 0, 0);
      }
    __builtin_amdgcn_s_setprio(0);
    __builtin_amdgcn_s_barrier();

    if (s2) { stB(t + 2, 2); stB(t + 2, 3); }
    __builtin_amdgcn_s_setprio(1);
#pragma unroll
    for (int m = 0; m < 4; ++m)
#pragma unroll
      for (int n = 0; n < 2; ++n) {
        acc[4 + m][n] = __builtin_amdgcn_mfma_f32_16x16x32_bf16(aH[m][0], b01[n][0], acc[4 + m][n], 0, 0, 0);
        acc[4 + m][n] = __builtin_amdgcn_mfma_f32_16x16x32_bf16(aH[m][1], b01[n][1], acc[4 + m][n], 0, 0, 0);
      }
    __builtin_amdgcn_s_setprio(0);
    if (s2)      asm volatile("s_waitcnt vmcnt(6)" ::: "memory");
    else if (s1) asm volatile("s_waitcnt vmcnt(0)" ::: "memory");
    __builtin_amdgcn_s_barrier();
  }

#pragma unroll
  for (int m = 0; m < 8; ++m) {
    const long row0 = tM + wm * 128 + m * 16 + lg * 4;
#pragma unroll
    for (int n = 0; n < 4; ++n) {
      const long col = tN + wn * 64 + n * 16 + l15;
      const float bc = BIASROW ? 0.f : bias[col];
#pragma unroll
      for (int e = 0; e < 4; ++e) {
        const long row = row0 + e;
        float v = acc[m][n][e] + (BIASROW ? bias[row] : bc);
        if constexpr (EPI == 1) v = 0.5f * v * (1.0f + erff(v * 0.70710678118654752f));
        if constexpr (EPI == 2) v += res[row * N + col];
        if constexpr (OUTBF) ((unsigned short*)outp)[row * N + col] = f2bf(v);
        else                 ((float*)outp)[row * N + col] = v;
      }
    }
  }
}

// ---------------- LayerNorm (f32 in, bf16 out), one block per row of 3072 ----------------
__global__ __launch_bounds__(256)
void ln_bf16(const float* __restrict__ x, const float* __restrict__ g,
             const float* __restrict__ b, unsigned short* __restrict__ out)
{
  __shared__ float red[4];
  const int tid = threadIdx.x;
  const long row = blockIdx.x;
  const float* xr = x + row * 3072;
  float4 v[3];
  float s = 0.f;
#pragma unroll
  for (int i = 0; i < 3; ++i) {
    v[i] = *(const float4*)&xr[i * 1024 + tid * 4];
    s += v[i].x + v[i].y + v[i].z + v[i].w;
  }
#pragma unroll
  for (int o = 32; o > 0; o >>= 1) s += __shfl_xor(s, o);
  if ((tid & 63) == 0) red[tid >> 6] = s;
  __syncthreads();
  s = red[0] + red[1] + red[2] + red[3];
  const float mean = s * (1.f / 3072.f);
  float vs = 0.f;
#pragma unroll
  for (int i = 0; i < 3; ++i) {
    const float dx = v[i].x - mean, dy = v[i].y - mean;
    const float dz = v[i].z - mean, dw = v[i].w - mean;
    vs += dx * dx + dy * dy + dz * dz + dw * dw;
  }
#pragma unroll
  for (int o = 32; o > 0; o >>= 1) vs += __shfl_xor(vs, o);
  __syncthreads();
  if ((tid & 63) == 0) red[tid >> 6] = vs;
  __syncthreads();
  vs = red[0] + red[1] + red[2] + red[3];
  const float rstd = rsqrtf(vs * (1.f / 3072.f) + 1e-5f);
#pragma unroll
  for (int i = 0; i < 3; ++i) {
    const int idx = i * 1024 + tid * 4;
    const float* vp = (const float*)&v[i];
    u16x4 o4;
#pragma unroll
    for (int c = 0; c < 4; ++c)
      o4[c] = f2bf((vp[c] - mean) * rstd * g[idx + c] + b[idx + c]);
    *(u16x4*)&out[row * 3072 + idx] = o4;
  }
}

// -------- fused weight prep v2: 64x64 tiles, float4 loads + u16x4 stores ----------------
__global__ __launch_bounds__(256)
void prep_weights(const float* __restrict__ Wq, const float* __restrict__ Wk,
                  const float* __restrict__ Wv, const float* __restrict__ Wo,
                  const float* __restrict__ W1, const float* __restrict__ W2,
                  const float* __restrict__ bq, const float* __restrict__ bk,
                  unsigned short* __restrict__ WqkT, unsigned short* __restrict__ WvT,
                  unsigned short* __restrict__ WoT, unsigned short* __restrict__ W1T,
                  unsigned short* __restrict__ W2T, float* __restrict__ bqk)
{
  __shared__ float tile[64][65];
  const int tid = threadIdx.x;
  int bid = blockIdx.x;
  if (bid < 24) {  // bias concat: 6144 floats
    const int i = bid * 256 + tid;
    bqk[i] = (i < 3072) ? bq[i] : bk[i - 3072];
    return;
  }
  bid -= 24;
  const float* in; unsigned short* out; int R, C, nbx;
  if (bid < 2304)       { in = Wq; out = WqkT;               R = 3072; C = 3072; nbx = 48; }
  else if (bid < 4608)  { in = Wk; out = WqkT + 3072 * 3072; R = 3072; C = 3072; nbx = 48; bid -= 2304; }
  else if (bid < 6912)  { in = Wv; out = WvT;                R = 3072; C = 3072; nbx = 48; bid -= 4608; }
  else if (bid < 9216)  { in = Wo; out = WoT;                R = 3072; C = 3072; nbx = 48; bid -= 6912; }
  else if (bid < 15360) { in = W1; out = W1T;                R = 3072; C = 8192; nbx = 128; bid -= 9216; }
  else                  { in = W2; out = W2T;                R = 8192; C = 3072; nbx = 48; bid -= 15360; }
  const int bx = bid % nbx, by = bid / nbx;
  const long r0 = (long)by * 64, c0 = (long)bx * 64;
  const int tr = tid >> 4;        // 0..15
  const int tc = (tid & 15) * 4;  // 0,4,..,60

#pragma unroll
  for (int p = 0; p < 4; ++p) {
    const int row = p * 16 + tr;
    const float4 v = *(const float4*)&in[(r0 + row) * C + c0 + tc];
    tile[row][tc + 0] = v.x; tile[row][tc + 1] = v.y;
    tile[row][tc + 2] = v.z; tile[row][tc + 3] = v.w;
  }
  __syncthreads();

#pragma unroll
  for (int q = 0; q < 4; ++q) {
    const int c = q * 16 + tr;
    u16x4 o4;
#pragma unroll
    for (int j = 0; j < 4; ++j)
      o4[j] = f2bf(tile[tc + j][c]);
    *(u16x4*)&out[(c0 + c) * R + r0 + tc] = o4;
  }
}

// ---------------- Flash attention fwd (Q-in-reg, T14 K/V reg-prefetch, defer-max) ----
__global__ __launch_bounds__(256, 4)
void attn_fwd(const unsigned short* __restrict__ qk,
              const unsigned short* __restrict__ vT,
              unsigned short* __restrict__ ctx)
{
  __shared__ unsigned short Ks[64 * 104];
  __shared__ unsigned short Vt[96 * 72];
  __shared__ unsigned short Ps[4 * 16 * 72];
  const int tid = threadIdx.x;
  const int lane = tid & 63;
  const int w = tid >> 6;
  const int l15 = lane & 15, lg = lane >> 4;
  const int bid = (blockIdx.x & 7) * 256 + (blockIdx.x >> 3);
  const int qb = bid & 31;
  const int h = (bid >> 5) & 31;
  const int b = bid >> 10;
  const long qkbase = ((long)b * 2048) * 6144 + h * 96;
  const long obase  = ((long)b * 2048) * 3072 + h * 96;
  const long vbase  = (long)(h * 96) * 4096 + (long)b * 2048;
  const int qbase = qb * 64;

  bfrag qf[3];
#pragma unroll
  for (int ks = 0; ks < 3; ++ks)
    qf[ks] = *(const bfrag*)&qk[qkbase + (long)(qbase + w * 16 + l15) * 6144 + ks * 32 + lg * 8];

  const int kr0 = tid / 12,         kk0 = (tid % 12) * 8;
  const int kr1 = (tid + 256) / 12, kk1 = ((tid + 256) % 12) * 8;
  const int kr2 = (tid + 512) / 12, kk2 = ((tid + 512) % 12) * 8;
  const unsigned short* kg = qk + qkbase + 3072;
  const int vd0 = tid >> 3,           vk0 = (tid & 7) * 8;
  const int vd1 = (tid + 256) >> 3,   vk1 = ((tid + 256) & 7) * 8;
  const int vd2 = (tid + 512) >> 3,   vk2 = ((tid + 512) & 7) * 8;
  const unsigned short* vg = vT + vbase;

  u16x8 kA = *(const u16x8*)&kg[(long)kr0 * 6144 + kk0];
  u16x8 kB = *(const u16x8*)&kg[(long)kr1 * 6144 + kk1];
  u16x8 kC = *(const u16x8*)&kg[(long)kr2 * 6144 + kk2];
  u16x8 vA = *(const u16x8*)&vg[(long)vd0 * 4096 + vk0];
  u16x8 vB = *(const u16x8*)&vg[(long)vd1 * 4096 + vk1];
  u16x8 vC = *(const u16x8*)&vg[(long)vd2 * 4096 + vk2];

  float m_run = -1e30f, l_run = 0.f;
  f4 O[6] = {};
  const float sc = 0.1020620726f * 1.4426950409f;  // 1/sqrt(96) * log2(e)

  for (int t = 0; t < 32; ++t) {
    *(u16x8*)&Ks[kr0 * 104 + kk0] = kA;
    *(u16x8*)&Ks[kr1 * 104 + kk1] = kB;
    *(u16x8*)&Ks[kr2 * 104 + kk2] = kC;
    *(u16x8*)&Vt[vd0 * 72 + vk0] = vA;
    *(u16x8*)&Vt[vd1 * 72 + vk1] = vB;
    *(u16x8*)&Vt[vd2 * 72 + vk2] = vC;
    __syncthreads();
    if (t + 1 < 32) {
      const long ko = (long)(t + 1) * 64 * 6144;
      const long vo = (long)(t + 1) * 64;
      kA = *(const u16x8*)&kg[ko + (long)kr0 * 6144 + kk0];
      kB = *(const u16x8*)&kg[ko + (long)kr1 * 6144 + kk1];
      kC = *(const u16x8*)&kg[ko + (long)kr2 * 6144 + kk2];
      vA = *(const u16x8*)&vg[vo + (long)vd0 * 4096 + vk0];
      vB = *(const u16x8*)&vg[vo + (long)vd1 * 4096 + vk1];
      vC = *(const u16x8*)&vg[vo + (long)vd2 * 4096 + vk2];
    }

    f4 sf[4];
#pragma unroll
    for (int mb = 0; mb < 4; ++mb) {
      f4 z = {0.f, 0.f, 0.f, 0.f};
      sf[mb] = z;
#pragma unroll
      for (int ks = 0; ks < 3; ++ks) {
        bfrag kf = *(const bfrag*)&Ks[(mb * 16 + l15) * 104 + ks * 32 + lg * 8];
        sf[mb] = __builtin_amdgcn_mfma_f32_16x16x32_bf16(kf, qf[ks], sf[mb], 0, 0, 0);
      }
    }
    float p[16];
    float tmax = -1e30f;
#pragma unroll
    for (int mb = 0; mb < 4; ++mb)
#pragma unroll
      for (int e = 0; e < 4; ++e) {
        const float sv = sf[mb][e] * sc;
        p[mb * 4 + e] = sv;
        tmax = fmaxf(tmax, sv);
      }
    tmax = fmaxf(tmax, __shfl_xor(tmax, 16));
    tmax = fmaxf(tmax, __shfl_xor(tmax, 32));
    const bool noskip = !__all(tmax - m_run <= 8.0f);
    float mnew = m_run, alpha = 1.0f;
    if (noskip) {
      mnew = fmaxf(m_run, tmax);
      alpha = exp2f(m_run - mnew);
    }
    float psum = 0.f;
#pragma unroll
    for (int i = 0; i < 16; ++i) {
      p[i] = exp2f(p[i] - mnew);
      psum += p[i];
    }
    psum += __shfl_xor(psum, 16);
    psum += __shfl_xor(psum, 32);
    l_run = l_run * alpha + psum;
    m_run = mnew;
#pragma unroll
    for (int mb = 0; mb < 4; ++mb) {
      u16x4 pw;
#pragma unroll
      for (int e = 0; e < 4; ++e) pw[e] = f2bf(p[mb * 4 + e]);
      *(u16x4*)&Ps[w * 1152 + l15 * 72 + mb * 16 + lg * 4] = pw;
    }
    if (noskip) {
      float aE[4];
#pragma unroll
      for (int e = 0; e < 4; ++e) aE[e] = __shfl(alpha, lg * 4 + e);
#pragma unroll
      for (int nb = 0; nb < 6; ++nb)
#pragma unroll
        for (int e = 0; e < 4; ++e) O[nb][e] *= aE[e];
    }
    bfrag pf[2];
#pragma unroll
    for (int ks = 0; ks < 2; ++ks)
      pf[ks] = *(const bfrag*)&Ps[w * 1152 + l15 * 72 + ks * 32 + lg * 8];
#pragma unroll
    for (int nb = 0; nb < 6; ++nb)
#pragma unroll
      for (int ks = 0; ks < 2; ++ks) {
        bfrag vf = *(const bfrag*)&Vt[(nb * 16 + l15) * 72 + ks * 32 + lg * 8];
        O[nb] = __builtin_amdgcn_mfma_f32_16x16x32_bf16(pf[ks], vf, O[nb], 0, 0, 0);
      }
    __syncthreads();
  }
  float lE[4];
#pragma unroll
  for (int e = 0; e < 4; ++e) lE[e] = 1.f / __shfl(l_run, lg * 4 + e);
#pragma unroll
  for (int nb = 0; nb < 6; ++nb)
#pragma unroll
    for (int e = 0; e < 4; ++e) {
      const long row = qbase + w * 16 + lg * 4 + e;
      ctx[obase + row * 3072 + nb * 16 + l15] = f2bf(O[nb][e] * lE[e]);
    }
}

// ---------------- driver ----------------
extern "C" void kernel_launch(void* const* d_in, const int* in_sizes, int n_in,
                              void* d_out, int out_size, void* d_ws, size_t ws_size,
                              hipStream_t stream)
{
  (void)in_sizes; (void)n_in; (void)out_size; (void)ws_size;
  const float* x    = (const float*)d_in[0];
  const float* ln1g = (const float*)d_in[1];
  const float* ln1b = (const float*)d_in[2];
  const float* Wq   = (const float*)d_in[3];
  const float* bq   = (const float*)d_in[4];
  const float* Wk   = (const float*)d_in[5];
  const float* bk   = (const float*)d_in[6];
  const float* Wv   = (const float*)d_in[7];
  const float* bv   = (const float*)d_in[8];
  const float* Wo   = (const float*)d_in[9];
  const float* bo   = (const float*)d_in[10];
  const float* ln2g = (const float*)d_in[11];
  const float* ln2b = (const float*)d_in[12];
  const float* W1   = (const float*)d_in[13];
  const float* b1   = (const float*)d_in[14];
  const float* W2   = (const float*)d_in[15];
  const float* b2   = (const float*)d_in[16];

  char* ws = (char*)d_ws;
  unsigned short* WqkT = (unsigned short*)(ws + 0);          // [6144][3072]
  unsigned short* WvT  = (unsigned short*)(ws + 37748736);   // [3072][3072]
  unsigned short* WoT  = (unsigned short*)(ws + 56623104);   // [3072][3072]
  unsigned short* W1T  = (unsigned short*)(ws + 75497472);   // [8192][3072]
  unsigned short* W2T  = (unsigned short*)(ws + 125829120);  // [3072][8192]
  float*          bqk  = (float*)(ws + 176160768);           // [6144]
  unsigned short* hbf  = (unsigned short*)(ws + 176185344);  // LN1 out; later ctx
  unsigned short* ctxb = hbf;
  unsigned short* qkb  = (unsigned short*)(ws + 201351168);  // [4096][6144]; later h2
  unsigned short* h2   = qkb;
  unsigned short* act  = (unsigned short*)(ws + 251682816);  // [4096][8192]
  unsigned short* vTb  = (unsigned short*)(ws + 318791680);  // [3072][4096]
  float*          h1   = (float*)d_out;                      // f32 residual lives in d_out

  const dim3 blk(256);
  const dim3 blk512(512);

  // weight prep: 24 bias blocks + 21504 transpose tiles (64x64)
  prep_weights<<<24 + 21504, blk, 0, stream>>>(Wq, Wk, Wv, Wo, W1, W2, bq, bk,
                                               WqkT, WvT, WoT, W1T, W2T, bqk);

  ln_bf16<<<4096, blk, 0, stream>>>(x, ln1g, ln1b, hbf);

  // fused Q+K projection (K=3072): gemm256, 16x24 tiles = 384 blocks, chunk 8x6
  gemm256<0, 1, 0><<<384, blk512, 0, stream>>>(hbf, WqkT, bqk, nullptr, qkb, 4096, 6144, 3072, 16, 8, 6);
  // V projection, swapped operands -> vT [3072][4096] (K=3072): 12x16 = 192, chunk 6x4
  gemm256<0, 1, 1><<<192, blk512, 0, stream>>>(WvT, hbf, bv, nullptr, vTb, 3072, 4096, 3072, 12, 6, 4);

  attn_fwd<<<2048, blk, 0, stream>>>(qkb, vTb, ctxb);

  // O projection + residual(x) -> h1 (f32, in d_out) (K=3072): 16x12 = 192, chunk 4x6
  gemm256<2, 0, 0><<<192, blk512, 0, stream>>>(ctxb, WoT, bo, x, h1, 4096, 3072, 3072, 16, 4, 6);

  ln_bf16<<<4096, blk, 0, stream>>>(h1, ln2g, ln2b, h2);

  // MLP up + GELU (K=3072): gemm256, 512 blocks = exactly 2 full machine rounds
  gemm256<1, 1, 0><<<512, blk512, 0, stream>>>(h2, W1T, b1, nullptr, act, 4096, 8192, 3072, 16, 8, 8);
  // MLP down + residual(h1, already in d_out) (K=8192): gemm_bt 768 blocks (R15-proven best)
  gemm_bt<2, 0, 0><<<768, blk, 0, stream>>>(act, W2T, b2, h1, (float*)d_out, 4096, 3072, 8192, 32, 16, 6);
}

// Round 18
// 1157.196 us; speedup vs baseline: 1.0473x; 1.0103x over previous
//
#include <hip/hip_runtime.h>
#include <math.h>

#define DEV __device__ __forceinline__

typedef __attribute__((ext_vector_type(8))) __bf16 bfrag;
typedef __attribute__((ext_vector_type(4))) float f4;
typedef __attribute__((ext_vector_type(8))) unsigned short u16x8;
typedef __attribute__((ext_vector_type(4))) unsigned short u16x4;

DEV unsigned short f2bf(float f) {
  // native RNE conversion — compiler fuses pairs into v_cvt_pk_bf16_f32 (m240)
  __bf16 b = (__bf16)f;
  unsigned short u;
  __builtin_memcpy(&u, &b, 2);
  return u;
}

DEV void gload_lds16(const void* g, void* l) {
  __builtin_amdgcn_global_load_lds((const __attribute__((address_space(1))) void*)g,
                                   (__attribute__((address_space(3))) void*)l, 16, 0, 0);
}

// ---------------- GEMM 128x128 (m97 structure + XCD chunk) — best for K=8192 ----------------
template<int EPI, int OUTBF, int BIASROW>
__global__ __launch_bounds__(256, 2)
void gemm_bt(const unsigned short* __restrict__ A,
             const unsigned short* __restrict__ Bt,
             const float* __restrict__ bias,
             const float* __restrict__ res,
             void* __restrict__ outp,
             int M, int N, int K, int gm, int cm, int cn)
{
  __shared__ unsigned short As[2][128 * 32];
  __shared__ unsigned short Bs[2][128 * 32];
  const int tid = threadIdx.x;
  const int lane = tid & 63;
  const int wid = tid >> 6;
  const int wr = wid >> 1, wc = wid & 1;
  const int l15 = lane & 15, lg = lane >> 4;

  const int xcd = blockIdx.x & 7, bidx = blockIdx.x >> 3;
  const int cgm = gm / cm;
  const int tm = (xcd % cgm) * cm + bidx % cm;
  const int tn = (xcd / cgm) * cn + bidx / cm;
  const long tM = (long)tm * 128;
  const long tN = (long)tn * 128;

  const int c0 = tid, c1 = tid + 256;
  const int r0 = c0 >> 2, k0 = (c0 & 3) * 8;
  const int r1 = c1 >> 2, k1 = (c1 & 3) * 8;

  const unsigned short* A0 = A + (tM + r0) * (long)K + k0;
  const unsigned short* A1 = A + (tM + r1) * (long)K + k1;
  const unsigned short* B0 = Bt + (tN + r0) * (long)K + k0;
  const unsigned short* B1 = Bt + (tN + r1) * (long)K + k1;

  auto stage = [&](int kt, int buf) {
    const long ko = (long)kt * 32;
    gload_lds16(A0 + ko, &As[buf][c0 * 8]);
    gload_lds16(A1 + ko, &As[buf][c1 * 8]);
    gload_lds16(B0 + ko, &Bs[buf][c0 * 8]);
    gload_lds16(B1 + ko, &Bs[buf][c1 * 8]);
  };

  stage(0, 0);
  f4 acc[4][4] = {};
  const int nk = K >> 5;
  int cur = 0;
  __syncthreads();
  for (int kt = 0; kt < nk; ++kt) {
    if (kt + 1 < nk) stage(kt + 1, cur ^ 1);
    bfrag aF[4], bF[4];
#pragma unroll
    for (int m = 0; m < 4; ++m)
      aF[m] = *(const bfrag*)&As[cur][(wr * 64 + m * 16 + l15) * 32 + lg * 8];
#pragma unroll
    for (int n = 0; n < 4; ++n)
      bF[n] = *(const bfrag*)&Bs[cur][(wc * 64 + n * 16 + l15) * 32 + lg * 8];
#pragma unroll
    for (int m = 0; m < 4; ++m)
#pragma unroll
      for (int n = 0; n < 4; ++n)
        acc[m][n] = __builtin_amdgcn_mfma_f32_16x16x32_bf16(aF[m], bF[n], acc[m][n], 0, 0, 0);
    __syncthreads();
    cur ^= 1;
  }

#pragma unroll
  for (int m = 0; m < 4; ++m) {
#pragma unroll
    for (int n = 0; n < 4; ++n) {
      const long col = tN + wc * 64 + n * 16 + l15;
      const float bcol = BIASROW ? 0.f : bias[col];
#pragma unroll
      for (int e = 0; e < 4; ++e) {
        const long row = tM + wr * 64 + m * 16 + lg * 4 + e;
        float v = acc[m][n][e] + (BIASROW ? bias[row] : bcol);
        if constexpr (EPI == 1) v = 0.5f * v * (1.0f + erff(v * 0.70710678118654752f));
        if constexpr (EPI == 2) v += res[row * N + col];
        if constexpr (OUTBF) ((unsigned short*)outp)[row * N + col] = f2bf(v);
        else                 ((float*)outp)[row * N + col] = v;
      }
    }
  }
}

// ============ 256x256 8-phase GEMM (R12 schedule, verified) — best for K=3072 ============
template<int EPI, int OUTBF, int BIASROW>
__global__ __launch_bounds__(512, 2)
void gemm256(const unsigned short* __restrict__ A,
             const unsigned short* __restrict__ Bt,
             const float* __restrict__ bias,
             const float* __restrict__ res,
             void* __restrict__ outp,
             int M, int N, int K, int gm, int cm, int cn)
{
  __shared__ unsigned short As[2][256 * 64];
  __shared__ unsigned short Bs[2][256 * 64];

  const int tid = threadIdx.x;
  const int lane = tid & 63;
  const int wid = tid >> 6;
  const int wm = wid >> 2, wn = wid & 3;
  const int l15 = lane & 15, lg = lane >> 4;

  const int xcd = blockIdx.x & 7, bidx = blockIdx.x >> 3;
  const int cgm = gm / cm;
  const int tm = (xcd % cgm) * cm + bidx % cm;
  const int tn = (xcd / cgm) * cn + bidx / cm;
  const long tM = (long)tm * 256, tN = (long)tn * 256;

  const int srow = tid >> 3;
  const int lslot = (tid & 7) ^ (srow & 7);
  const unsigned short* aSrc = A + (tM + srow) * (long)K + lslot * 8;
  const unsigned short* bSrc = Bt + (tN + srow) * (long)K + lslot * 8;
  const int NT = K >> 6;

  auto stA = [&](int t, int j) {
    gload_lds16(aSrc + (long)t * 64 + (long)j * 64 * K, &As[t & 1][j * 4096 + tid * 8]);
  };
  auto stB = [&](int t, int j) {
    gload_lds16(bSrc + (long)t * 64 + (long)j * 64 * K, &Bs[t & 1][j * 4096 + tid * 8]);
  };

#pragma unroll
  for (int j = 0; j < 4; ++j) stA(0, j);
#pragma unroll
  for (int j = 0; j < 4; ++j) stB(0, j);
  stA(1, 0); stA(1, 2);
#pragma unroll
  for (int j = 0; j < 4; ++j) stB(1, j);
  asm volatile("s_waitcnt vmcnt(6)" ::: "memory");
  __builtin_amdgcn_s_barrier();

  const int aRow = (wm * 128 + l15) * 64;
  const int bRow = (wn * 64 + l15) * 64;
  const int sx = l15 & 7;
  const int sl0 = ((0 + lg) ^ sx) * 8;
  const int sl1 = ((4 + lg) ^ sx) * 8;

  bfrag aL[4][2], aH[4][2], b01[2][2], b23[2][2];
  f4 acc[8][4] = {};

  int cur = 0;
  for (int t = 0; t < NT; ++t, cur ^= 1) {
    const unsigned short* Ac = As[cur];
    const unsigned short* Bc = Bs[cur];
    const bool s1 = (t + 1 < NT);
    const bool s2 = (t + 2 < NT);

#pragma unroll
    for (int m = 0; m < 4; ++m) {
      aL[m][0] = *(const bfrag*)&Ac[aRow + m * 1024 + sl0];
      aL[m][1] = *(const bfrag*)&Ac[aRow + m * 1024 + sl1];
    }
#pragma unroll
    for (int n = 0; n < 2; ++n) {
      b01[n][0] = *(const bfrag*)&Bc[bRow + n * 1024 + sl0];
      b01[n][1] = *(const bfrag*)&Bc[bRow + n * 1024 + sl1];
    }
#pragma unroll
    for (int n = 0; n < 2; ++n) {
      b23[n][0] = *(const bfrag*)&Bc[bRow + (n + 2) * 1024 + sl0];
      b23[n][1] = *(const bfrag*)&Bc[bRow + (n + 2) * 1024 + sl1];
    }
    if (s1) { stA(t + 1, 1); stA(t + 1, 3); }
    __builtin_amdgcn_s_barrier();
    __builtin_amdgcn_s_setprio(1);
#pragma unroll
    for (int m = 0; m < 4; ++m)
#pragma unroll
      for (int n = 0; n < 2; ++n) {
        acc[m][n] = __builtin_amdgcn_mfma_f32_16x16x32_bf16(aL[m][0], b01[n][0], acc[m][n], 0, 0, 0);
        acc[m][n] = __builtin_amdgcn_mfma_f32_16x16x32_bf16(aL[m][1], b01[n][1], acc[m][n], 0, 0, 0);
      }
    __builtin_amdgcn_s_setprio(0);
    __builtin_amdgcn_s_barrier();

#pragma unroll
    for (int m = 0; m < 4; ++m) {
      aH[m][0] = *(const bfrag*)&Ac[aRow + 4096 + m * 1024 + sl0];
      aH[m][1] = *(const bfrag*)&Ac[aRow + 4096 + m * 1024 + sl1];
    }
    if (s2) { stA(t + 2, 0); stA(t + 2, 2); }
    __builtin_amdgcn_s_barrier();
    __builtin_amdgcn_s_setprio(1);
#pragma unroll
    for (int m = 0; m < 4; ++m)
#pragma unroll
      for (int n = 0; n < 2; ++n) {
        acc[m][2 + n] = __builtin_amdgcn_mfma_f32_16x16x32_bf16(aL[m][0], b23[n][0], acc[m][2 + n], 0, 0, 0);
        acc[m][2 + n] = __builtin_amdgcn_mfma_f32_16x16x32_bf16(aL[m][1], b23[n][1], acc[m][2 + n], 0, 0, 0);
      }
    __builtin_amdgcn_s_setprio(0);
    __builtin_amdgcn_s_barrier();

    if (s2) { stB(t + 2, 0); stB(t + 2, 1); }
    __builtin_amdgcn_s_barrier();
    __builtin_amdgcn_s_setprio(1);
#pragma unroll
    for (int m = 0; m < 4; ++m)
#pragma unroll
      for (int n = 0; n < 2; ++n) {
        acc[4 + m][2 + n] = __builtin_amdgcn_mfma_f32_16x16x32_bf16(aH[m][0], b23[n][0], acc[4 + m][2 + n], 0, 0, 0);
        acc[4 + m][2 + n] = __builtin_amdgcn_mfma_f32_16x16x32_bf16(aH[m][1], b23[n][1], acc[4 + m][2 + n], 0, 0, 0);
      }
    __builtin_amdgcn_s_setprio(0);
    __builtin_amdgcn_s_barrier();

    if (s2) { stB(t + 2, 2); stB(t + 2, 3); }
    __builtin_amdgcn_s_setprio(1);
#pragma unroll
    for (int m = 0; m < 4; ++m)
#pragma unroll
      for (int n = 0; n < 2; ++n) {
        acc[4 + m][n] = __builtin_amdgcn_mfma_f32_16x16x32_bf16(aH[m][0], b01[n][0], acc[4 + m][n], 0, 0, 0);
        acc[4 + m][n] = __builtin_amdgcn_mfma_f32_16x16x32_bf16(aH[m][1], b01[n][1], acc[4 + m][n], 0, 0, 0);
      }
    __builtin_amdgcn_s_setprio(0);
    if (s2)      asm volatile("s_waitcnt vmcnt(6)" ::: "memory");
    else if (s1) asm volatile("s_waitcnt vmcnt(0)" ::: "memory");
    __builtin_amdgcn_s_barrier();
  }

#pragma unroll
  for (int m = 0; m < 8; ++m) {
    const long row0 = tM + wm * 128 + m * 16 + lg * 4;
#pragma unroll
    for (int n = 0; n < 4; ++n) {
      const long col = tN + wn * 64 + n * 16 + l15;
      const float bc = BIASROW ? 0.f : bias[col];
#pragma unroll
      for (int e = 0; e < 4; ++e) {
        const long row = row0 + e;
        float v = acc[m][n][e] + (BIASROW ? bias[row] : bc);
        if constexpr (EPI == 1) v = 0.5f * v * (1.0f + erff(v * 0.70710678118654752f));
        if constexpr (EPI == 2) v += res[row * N + col];
        if constexpr (OUTBF) ((unsigned short*)outp)[row * N + col] = f2bf(v);
        else                 ((float*)outp)[row * N + col] = v;
      }
    }
  }
}

// ---------------- LayerNorm (f32 in, bf16 out), one block per row of 3072 ----------------
__global__ __launch_bounds__(256)
void ln_bf16(const float* __restrict__ x, const float* __restrict__ g,
             const float* __restrict__ b, unsigned short* __restrict__ out)
{
  __shared__ float red[4];
  const int tid = threadIdx.x;
  const long row = blockIdx.x;
  const float* xr = x + row * 3072;
  float4 v[3];
  float s = 0.f;
#pragma unroll
  for (int i = 0; i < 3; ++i) {
    v[i] = *(const float4*)&xr[i * 1024 + tid * 4];
    s += v[i].x + v[i].y + v[i].z + v[i].w;
  }
#pragma unroll
  for (int o = 32; o > 0; o >>= 1) s += __shfl_xor(s, o);
  if ((tid & 63) == 0) red[tid >> 6] = s;
  __syncthreads();
  s = red[0] + red[1] + red[2] + red[3];
  const float mean = s * (1.f / 3072.f);
  float vs = 0.f;
#pragma unroll
  for (int i = 0; i < 3; ++i) {
    const float dx = v[i].x - mean, dy = v[i].y - mean;
    const float dz = v[i].z - mean, dw = v[i].w - mean;
    vs += dx * dx + dy * dy + dz * dz + dw * dw;
  }
#pragma unroll
  for (int o = 32; o > 0; o >>= 1) vs += __shfl_xor(vs, o);
  __syncthreads();
  if ((tid & 63) == 0) red[tid >> 6] = vs;
  __syncthreads();
  vs = red[0] + red[1] + red[2] + red[3];
  const float rstd = rsqrtf(vs * (1.f / 3072.f) + 1e-5f);
#pragma unroll
  for (int i = 0; i < 3; ++i) {
    const int idx = i * 1024 + tid * 4;
    const float* vp = (const float*)&v[i];
    u16x4 o4;
#pragma unroll
    for (int c = 0; c < 4; ++c)
      o4[c] = f2bf((vp[c] - mean) * rstd * g[idx + c] + b[idx + c]);
    *(u16x4*)&out[row * 3072 + idx] = o4;
  }
}

// -------- fused weight prep v2: 64x64 tiles, float4 loads + u16x4 stores ----------------
__global__ __launch_bounds__(256)
void prep_weights(const float* __restrict__ Wq, const float* __restrict__ Wk,
                  const float* __restrict__ Wv, const float* __restrict__ Wo,
                  const float* __restrict__ W1, const float* __restrict__ W2,
                  const float* __restrict__ bq, const float* __restrict__ bk,
                  unsigned short* __restrict__ WqkT, unsigned short* __restrict__ WvT,
                  unsigned short* __restrict__ WoT, unsigned short* __restrict__ W1T,
                  unsigned short* __restrict__ W2T, float* __restrict__ bqk)
{
  __shared__ float tile[64][65];
  const int tid = threadIdx.x;
  int bid = blockIdx.x;
  if (bid < 24) {  // bias concat: 6144 floats
    const int i = bid * 256 + tid;
    bqk[i] = (i < 3072) ? bq[i] : bk[i - 3072];
    return;
  }
  bid -= 24;
  const float* in; unsigned short* out; int R, C, nbx;
  if (bid < 2304)       { in = Wq; out = WqkT;               R = 3072; C = 3072; nbx = 48; }
  else if (bid < 4608)  { in = Wk; out = WqkT + 3072 * 3072; R = 3072; C = 3072; nbx = 48; bid -= 2304; }
  else if (bid < 6912)  { in = Wv; out = WvT;                R = 3072; C = 3072; nbx = 48; bid -= 4608; }
  else if (bid < 9216)  { in = Wo; out = WoT;                R = 3072; C = 3072; nbx = 48; bid -= 6912; }
  else if (bid < 15360) { in = W1; out = W1T;                R = 3072; C = 8192; nbx = 128; bid -= 9216; }
  else                  { in = W2; out = W2T;                R = 8192; C = 3072; nbx = 48; bid -= 15360; }
  const int bx = bid % nbx, by = bid / nbx;
  const long r0 = (long)by * 64, c0 = (long)bx * 64;
  const int tr = tid >> 4;        // 0..15
  const int tc = (tid & 15) * 4;  // 0,4,..,60

#pragma unroll
  for (int p = 0; p < 4; ++p) {
    const int row = p * 16 + tr;
    const float4 v = *(const float4*)&in[(r0 + row) * C + c0 + tc];
    tile[row][tc + 0] = v.x; tile[row][tc + 1] = v.y;
    tile[row][tc + 2] = v.z; tile[row][tc + 3] = v.w;
  }
  __syncthreads();

#pragma unroll
  for (int q = 0; q < 4; ++q) {
    const int c = q * 16 + tr;
    u16x4 o4;
#pragma unroll
    for (int j = 0; j < 4; ++j)
      o4[j] = f2bf(tile[tc + j][c]);
    *(u16x4*)&out[(c0 + c) * R + r0 + tc] = o4;
  }
}

// ---------------- Flash attention fwd (R18: QBLK=128 via 8 waves, ONE q-set per wave) ----
// qk bf16 [B,S,6144]; vT bf16 [3072][B*S]; ctx bf16 [B,S,3072]
// 512 thr (8 waves) share one K/V tile; per-wave softmax chain identical to R14.
// Staging per q-row halves (1024 blocks); 45.5KB LDS -> 3 blocks/CU = 24 waves/CU.
__global__ __launch_bounds__(512, 4)
void attn_fwd(const unsigned short* __restrict__ qk,
              const unsigned short* __restrict__ vT,
              unsigned short* __restrict__ ctx)
{
  __shared__ unsigned short Ks[64 * 104];
  __shared__ unsigned short Vt[96 * 72];
  __shared__ unsigned short Ps[8 * 16 * 72];
  const int tid = threadIdx.x;
  const int lane = tid & 63;
  const int w = tid >> 6;          // 0..7
  const int l15 = lane & 15, lg = lane >> 4;
  const int bid = (blockIdx.x & 7) * 128 + (blockIdx.x >> 3);
  const int qb = bid & 15;
  const int h = (bid >> 4) & 31;
  const int b = bid >> 9;
  const long qkbase = ((long)b * 2048) * 6144 + h * 96;
  const long obase  = ((long)b * 2048) * 3072 + h * 96;
  const long vbase  = (long)(h * 96) * 4096 + (long)b * 2048;
  const int qbase = qb * 128;

  // Q hoisted to registers (wave w owns q-rows qbase + w*16 + l15)
  bfrag qf[3];
#pragma unroll
  for (int ks = 0; ks < 3; ++ks)
    qf[ks] = *(const bfrag*)&qk[qkbase + (long)(qbase + w * 16 + l15) * 6144 + ks * 32 + lg * 8];

  // K/V staging: 768 u16x8 chunks each, over 512 threads.
  // chunk A = tid (all threads); chunk B = tid + 512 (waves 0-3 only, wave-uniform).
  const bool two = (w < 4);
  const int kcA = tid, kcB = tid + 512;
  const int krA = kcA / 12, kkA = (kcA % 12) * 8;
  const int krB = kcB / 12, kkB = (kcB % 12) * 8;
  const unsigned short* kg = qk + qkbase + 3072;
  const int vdA = kcA >> 3, vkA = (kcA & 7) * 8;
  const int vdB = kcB >> 3, vkB = (kcB & 7) * 8;
  const unsigned short* vg = vT + vbase;

  u16x8 kA = *(const u16x8*)&kg[(long)krA * 6144 + kkA];
  u16x8 vA = *(const u16x8*)&vg[(long)vdA * 4096 + vkA];
  u16x8 kB, vB;
  if (two) {
    kB = *(const u16x8*)&kg[(long)krB * 6144 + kkB];
    vB = *(const u16x8*)&vg[(long)vdB * 4096 + vkB];
  }

  float m_run = -1e30f, l_run = 0.f;
  f4 O[6] = {};
  const float sc = 0.1020620726f * 1.4426950409f;  // 1/sqrt(96) * log2(e)

  for (int t = 0; t < 32; ++t) {
    *(u16x8*)&Ks[krA * 104 + kkA] = kA;
    *(u16x8*)&Vt[vdA * 72 + vkA] = vA;
    if (two) {
      *(u16x8*)&Ks[krB * 104 + kkB] = kB;
      *(u16x8*)&Vt[vdB * 72 + vkB] = vB;
    }
    __syncthreads();
    if (t + 1 < 32) {
      const long ko = (long)(t + 1) * 64 * 6144;
      const long vo = (long)(t + 1) * 64;
      kA = *(const u16x8*)&kg[ko + (long)krA * 6144 + kkA];
      vA = *(const u16x8*)&vg[vo + (long)vdA * 4096 + vkA];
      if (two) {
        kB = *(const u16x8*)&kg[ko + (long)krB * 6144 + kkB];
        vB = *(const u16x8*)&vg[vo + (long)vdB * 4096 + vkB];
      }
    }

    // QK^T (swapped): sf[mb][e] = S[k = mb*16 + lg*4 + e][q = l15]
    f4 sf[4];
#pragma unroll
    for (int mb = 0; mb < 4; ++mb) {
      f4 z = {0.f, 0.f, 0.f, 0.f};
      sf[mb] = z;
#pragma unroll
      for (int ks = 0; ks < 3; ++ks) {
        bfrag kf = *(const bfrag*)&Ks[(mb * 16 + l15) * 104 + ks * 32 + lg * 8];
        sf[mb] = __builtin_amdgcn_mfma_f32_16x16x32_bf16(kf, qf[ks], sf[mb], 0, 0, 0);
      }
    }
    float p[16];
    float tmax = -1e30f;
#pragma unroll
    for (int mb = 0; mb < 4; ++mb)
#pragma unroll
      for (int e = 0; e < 4; ++e) {
        const float sv = sf[mb][e] * sc;
        p[mb * 4 + e] = sv;
        tmax = fmaxf(tmax, sv);
      }
    tmax = fmaxf(tmax, __shfl_xor(tmax, 16));
    tmax = fmaxf(tmax, __shfl_xor(tmax, 32));
    const bool noskip = !__all(tmax - m_run <= 8.0f);
    float mnew = m_run, alpha = 1.0f;
    if (noskip) {
      mnew = fmaxf(m_run, tmax);
      alpha = exp2f(m_run - mnew);
    }
    float psum = 0.f;
#pragma unroll
    for (int i = 0; i < 16; ++i) {
      p[i] = exp2f(p[i] - mnew);
      psum += p[i];
    }
    psum += __shfl_xor(psum, 16);
    psum += __shfl_xor(psum, 32);
    l_run = l_run * alpha + psum;
    m_run = mnew;
#pragma unroll
    for (int mb = 0; mb < 4; ++mb) {
      u16x4 pw;
#pragma unroll
      for (int e = 0; e < 4; ++e) pw[e] = f2bf(p[mb * 4 + e]);
      *(u16x4*)&Ps[w * 1152 + l15 * 72 + mb * 16 + lg * 4] = pw;
    }
    if (noskip) {
      float aE[4];
#pragma unroll
      for (int e = 0; e < 4; ++e) aE[e] = __shfl(alpha, lg * 4 + e);
#pragma unroll
      for (int nb = 0; nb < 6; ++nb)
#pragma unroll
        for (int e = 0; e < 4; ++e) O[nb][e] *= aE[e];
    }
    bfrag pf[2];
#pragma unroll
    for (int ks = 0; ks < 2; ++ks)
      pf[ks] = *(const bfrag*)&Ps[w * 1152 + l15 * 72 + ks * 32 + lg * 8];
#pragma unroll
    for (int nb = 0; nb < 6; ++nb)
#pragma unroll
      for (int ks = 0; ks < 2; ++ks) {
        bfrag vf = *(const bfrag*)&Vt[(nb * 16 + l15) * 72 + ks * 32 + lg * 8];
        O[nb] = __builtin_amdgcn_mfma_f32_16x16x32_bf16(pf[ks], vf, O[nb], 0, 0, 0);
      }
    __syncthreads();
  }
  float lE[4];
#pragma unroll
  for (int e = 0; e < 4; ++e) lE[e] = 1.f / __shfl(l_run, lg * 4 + e);
#pragma unroll
  for (int nb = 0; nb < 6; ++nb)
#pragma unroll
    for (int e = 0; e < 4; ++e) {
      const long row = qbase + w * 16 + lg * 4 + e;
      ctx[obase + row * 3072 + nb * 16 + l15] = f2bf(O[nb][e] * lE[e]);
    }
}

// ---------------- driver ----------------
extern "C" void kernel_launch(void* const* d_in, const int* in_sizes, int n_in,
                              void* d_out, int out_size, void* d_ws, size_t ws_size,
                              hipStream_t stream)
{
  (void)in_sizes; (void)n_in; (void)out_size; (void)ws_size;
  const float* x    = (const float*)d_in[0];
  const float* ln1g = (const float*)d_in[1];
  const float* ln1b = (const float*)d_in[2];
  const float* Wq   = (const float*)d_in[3];
  const float* bq   = (const float*)d_in[4];
  const float* Wk   = (const float*)d_in[5];
  const float* bk   = (const float*)d_in[6];
  const float* Wv   = (const float*)d_in[7];
  const float* bv   = (const float*)d_in[8];
  const float* Wo   = (const float*)d_in[9];
  const float* bo   = (const float*)d_in[10];
  const float* ln2g = (const float*)d_in[11];
  const float* ln2b = (const float*)d_in[12];
  const float* W1   = (const float*)d_in[13];
  const float* b1   = (const float*)d_in[14];
  const float* W2   = (const float*)d_in[15];
  const float* b2   = (const float*)d_in[16];

  char* ws = (char*)d_ws;
  unsigned short* WqkT = (unsigned short*)(ws + 0);          // [6144][3072]
  unsigned short* WvT  = (unsigned short*)(ws + 37748736);   // [3072][3072]
  unsigned short* WoT  = (unsigned short*)(ws + 56623104);   // [3072][3072]
  unsigned short* W1T  = (unsigned short*)(ws + 75497472);   // [8192][3072]
  unsigned short* W2T  = (unsigned short*)(ws + 125829120);  // [3072][8192]
  float*          bqk  = (float*)(ws + 176160768);           // [6144]
  unsigned short* hbf  = (unsigned short*)(ws + 176185344);  // LN1 out; later ctx
  unsigned short* ctxb = hbf;
  unsigned short* qkb  = (unsigned short*)(ws + 201351168);  // [4096][6144]; later h2
  unsigned short* h2   = qkb;
  unsigned short* act  = (unsigned short*)(ws + 251682816);  // [4096][8192]
  unsigned short* vTb  = (unsigned short*)(ws + 318791680);  // [3072][4096]
  float*          h1   = (float*)d_out;                      // f32 residual lives in d_out

  const dim3 blk(256);
  const dim3 blk512(512);

  // weight prep: 24 bias blocks + 21504 transpose tiles (64x64)
  prep_weights<<<24 + 21504, blk, 0, stream>>>(Wq, Wk, Wv, Wo, W1, W2, bq, bk,
                                               WqkT, WvT, WoT, W1T, W2T, bqk);

  ln_bf16<<<4096, blk, 0, stream>>>(x, ln1g, ln1b, hbf);

  // fused Q+K projection (K=3072): gemm256, 16x24 tiles = 384 blocks, chunk 8x6
  gemm256<0, 1, 0><<<384, blk512, 0, stream>>>(hbf, WqkT, bqk, nullptr, qkb, 4096, 6144, 3072, 16, 8, 6);
  // V projection, swapped operands -> vT [3072][4096] (K=3072): 12x16 = 192, chunk 6x4
  gemm256<0, 1, 1><<<192, blk512, 0, stream>>>(WvT, hbf, bv, nullptr, vTb, 3072, 4096, 3072, 12, 6, 4);

  attn_fwd<<<1024, blk512, 0, stream>>>(qkb, vTb, ctxb);

  // O projection + residual(x) -> h1 (f32, in d_out) (K=3072): 16x12 = 192, chunk 4x6
  gemm256<2, 0, 0><<<192, blk512, 0, stream>>>(ctxb, WoT, bo, x, h1, 4096, 3072, 3072, 16, 4, 6);

  ln_bf16<<<4096, blk, 0, stream>>>(h1, ln2g, ln2b, h2);

  // MLP up + GELU (K=3072): gemm256, 512 blocks = exactly 2 full machine rounds
  gemm256<1, 1, 0><<<512, blk512, 0, stream>>>(h2, W1T, b1, nullptr, act, 4096, 8192, 3072, 16, 8, 8);
  // MLP down + residual(h1, already in d_out) (K=8192): gemm_bt 768 blocks (R15-proven best)
  gemm_bt<2, 0, 0><<<768, blk, 0, stream>>>(act, W2T, b2, h1, (float*)d_out, 4096, 3072, 8192, 32, 16, 6);
}